// Round 10
// baseline (523.585 us; speedup 1.0000x reference)
//
#include <hip/hip_runtime.h>
#include <math.h>

#define D_IN 64
#define D_H 40
#define D_OUT 24
#define S_BITS 8
#define S_NODES 256      // nodes per bucket
#define CH 8192          // edges per passA/passB block
#define BMAX 512         // max buckets (n <= 131072)

typedef unsigned int u32;
typedef unsigned short u16;

// ---------------- CSR build: atomic-free LDS multisplit ----------------
__global__ void passA(const int* __restrict__ dst, int* __restrict__ G,
                      int E, int B) {
    __shared__ int hist[BMAX];
    int tx = threadIdx.x;
    for (int i = tx; i < B; i += 256) hist[i] = 0;
    __syncthreads();
    int e0 = blockIdx.x * CH;
    int e1 = min(e0 + CH, E);
    for (int e = e0 + tx; e < e1; e += 256)
        atomicAdd(&hist[dst[e] >> S_BITS], 1);      // LDS atomic
    __syncthreads();
    for (int i = tx; i < B; i += 256) G[(size_t)blockIdx.x * B + i] = hist[i];
}

__global__ void colscan(int* __restrict__ G, int* __restrict__ bktTotal,
                        int NB1, int B) {
    int b = blockIdx.x;
    int lane = threadIdx.x;      // 64 threads
    int carry = 0;
    for (int base = 0; base < NB1; base += 64) {
        int i = base + lane;
        int orig = (i < NB1) ? G[(size_t)i * B + b] : 0;
        int v = orig;
        #pragma unroll
        for (int d = 1; d < 64; d <<= 1) {
            int t = __shfl_up(v, d);
            if (lane >= d) v += t;
        }
        if (i < NB1) G[(size_t)i * B + b] = carry + v - orig;   // exclusive
        carry += __shfl(v, 63);
    }
    if (lane == 0) bktTotal[b] = carry;
}

__global__ void bucketscan(const int* __restrict__ bktTotal,
                           int* __restrict__ bktStart, int* __restrict__ off,
                           int B, int E, int n) {
    int lane = threadIdx.x;
    int carry = 0;
    for (int base = 0; base < B; base += 64) {
        int i = base + lane;
        int orig = (i < B) ? bktTotal[i] : 0;
        int v = orig;
        #pragma unroll
        for (int d = 1; d < 64; d <<= 1) {
            int t = __shfl_up(v, d);
            if (lane >= d) v += t;
        }
        if (i < B) bktStart[i] = carry + v - orig;
        carry += __shfl(v, 63);
    }
    if (lane == 0) { bktStart[B] = carry; off[n] = E; }
}

__global__ void passB(const int* __restrict__ src, const int* __restrict__ dst,
                      const int* __restrict__ G, const int* __restrict__ bktStart,
                      u32* __restrict__ bucketed, int E, int B) {
    __shared__ int baseS[BMAX];
    __shared__ int cnt[BMAX];
    int tx = threadIdx.x;
    for (int i = tx; i < B; i += 256) {
        baseS[i] = bktStart[i] + G[(size_t)blockIdx.x * B + i];
        cnt[i] = 0;
    }
    __syncthreads();
    int e0 = blockIdx.x * CH;
    int e1 = min(e0 + CH, E);
    for (int e = e0 + tx; e < e1; e += 256) {
        int d = dst[e];
        int b = d >> S_BITS;
        int r = atomicAdd(&cnt[b], 1);               // LDS atomic
        bucketed[baseS[b] + r] = ((u32)(d & (S_NODES - 1)) << 24) | (u32)src[e];
    }
}

__global__ void bucket_csr(const u32* __restrict__ bucketed,
                           const int* __restrict__ bktStart,
                           int* __restrict__ off, int* __restrict__ csr,
                           int n) {
    __shared__ int degl[S_NODES];
    __shared__ int offl[S_NODES + 1];
    __shared__ int cntl[S_NODES];
    int b  = blockIdx.x;
    int tx = threadIdx.x;        // 256
    int bs = bktStart[b], be = bktStart[b + 1];
    degl[tx] = 0;
    cntl[tx] = 0;
    __syncthreads();
    for (int e = bs + tx; e < be; e += 256)
        atomicAdd(&degl[bucketed[e] >> 24], 1);      // LDS atomic
    __syncthreads();
    int v = degl[tx];
    offl[tx] = v;
    __syncthreads();
    for (int d = 1; d < 256; d <<= 1) {
        int t = (tx >= d) ? offl[tx - d] : 0;
        __syncthreads();
        offl[tx] += t;
        __syncthreads();
    }
    int excl = offl[tx] - v;
    __syncthreads();
    offl[tx] = excl;
    if (tx == 255) offl[256] = excl + v;
    __syncthreads();
    int node = b * S_NODES + tx;
    if (node <= n) off[node] = bs + offl[tx];
    for (int e = bs + tx; e < be; e += 256) {
        u32 w = bucketed[e];
        int dl = w >> 24;
        int r = atomicAdd(&cntl[dl], 1);             // LDS atomic
        csr[bs + offl[dl] + r] = (int)(w & 0xFFFFFFu);
    }
}

// ---------------- bf16 helpers ----------------
__device__ inline u16 f32_to_bf16_rne(float f) {
    u32 u = __float_as_uint(f);
    u += 0x7fffu + ((u >> 16) & 1u);
    return (u16)(u >> 16);
}

__device__ inline void accum8(float* a, uint4 w) {
    a[0] += __uint_as_float(w.x << 16);
    a[1] += __uint_as_float(w.x & 0xffff0000u);
    a[2] += __uint_as_float(w.y << 16);
    a[3] += __uint_as_float(w.y & 0xffff0000u);
    a[4] += __uint_as_float(w.z << 16);
    a[5] += __uint_as_float(w.z & 0xffff0000u);
    a[6] += __uint_as_float(w.w << 16);
    a[7] += __uint_as_float(w.w & 0xffff0000u);
}

__device__ inline float dot16(const float4* __restrict__ w, const float4* v) {
    float acc = 0.0f;
    #pragma unroll
    for (int k = 0; k < 16; ++k) {
        float4 a = w[k], b = v[k];
        acc += a.x * b.x + a.y * b.y + a.z * b.z + a.w * b.w;
    }
    return acc;
}

__device__ inline float dot10(const float4* __restrict__ w, const float4* v) {
    float acc = 0.0f;
    #pragma unroll
    for (int k = 0; k < 10; ++k) {
        float4 a = w[k], b = v[k];
        acc += a.x * b.x + a.y * b.y + a.z * b.z + a.w * b.w;
    }
    return acc;
}

// ---------------- pre1: xl = bf16(x@W1l^T), xr = x@W1r^T + b1 ----------------
// Block = 64 nodes x 4 waves. Wave w computes outputs [w*10, w*10+10) for all
// 64 nodes (lane = node): weight rows stay wave-uniform (scalar loads), and
// outputs are staged in LDS then written fully coalesced (kills the 8x
// partial-line write amplification of the row-per-thread version).
__global__ void pre1(const float* __restrict__ x, const float* __restrict__ W1l,
                     const float* __restrict__ W1r, const float* __restrict__ b1,
                     u32* __restrict__ xl, float* __restrict__ xr, int n) {
    __shared__ u32   xls[64][21];   // 20 used + pad (odd stride: conflict-free)
    __shared__ float xrs[64][41];   // 40 used + pad
    int tx = threadIdx.x;
    int w  = tx >> 6;        // wave 0..3 -> output slice
    int l  = tx & 63;        // lane = local node
    int node = blockIdx.x * 64 + l;
    float4 xv[16];
    if (node < n) {
        const float4* xp = (const float4*)(x + (size_t)node * D_IN);
        #pragma unroll
        for (int k = 0; k < 16; ++k) xv[k] = xp[k];
    } else {
        #pragma unroll
        for (int k = 0; k < 16; ++k) xv[k] = make_float4(0.f, 0.f, 0.f, 0.f);
    }
    int obase = w * 10;
    #pragma unroll
    for (int j = 0; j < 10; j += 2) {
        int o = obase + j;
        float al0 = dot16((const float4*)(W1l + o * D_IN), xv);
        float al1 = dot16((const float4*)(W1l + (o + 1) * D_IN), xv);
        float ar0 = dot16((const float4*)(W1r + o * D_IN), xv);
        float ar1 = dot16((const float4*)(W1r + (o + 1) * D_IN), xv);
        xls[l][o >> 1] = (u32)f32_to_bf16_rne(al0) | ((u32)f32_to_bf16_rne(al1) << 16);
        xrs[l][o]     = ar0 + b1[o];
        xrs[l][o + 1] = ar1 + b1[o + 1];
    }
    __syncthreads();
    int nodes = min(64, n - blockIdx.x * 64);
    u32*   xlb = xl + (size_t)blockIdx.x * 64 * 20;
    float* xrb = xr + (size_t)blockIdx.x * 64 * 40;
    for (int i = tx; i < nodes * 20; i += 256) {
        int nn = i / 20, c = i - nn * 20;
        xlb[i] = xls[nn][c];
    }
    for (int i = tx; i < nodes * 40; i += 256) {
        int nn = i / 40, c = i - nn * 40;
        xrb[i] = xrs[nn][c];
    }
}

// ---------------- Layer 1: h = relu(mean_gather(xl) + xr), in-place on xr ----
__global__ void gather_node1(const u32* __restrict__ xlp,
                             const int* __restrict__ off,
                             const int* __restrict__ csr,
                             float* __restrict__ hbuf,  // xr in, h out (n x 40)
                             int n) {
    __shared__ __align__(16) float part[4][12][D_H];
    int local = threadIdx.x >> 6;
    int lane  = threadIdx.x & 63;
    int node  = blockIdx.x * 4 + local;
    int g = lane / 5;
    int t = lane - g * 5;
    int deg = 0;
    const uint4* rows = (const uint4*)xlp;   // 5 uint4 per row
    if (node < n) {
        int o0 = off[node], o1 = off[node + 1];
        deg = o1 - o0;
        float a0[8] = {0,0,0,0,0,0,0,0};
        float a1[8] = {0,0,0,0,0,0,0,0};
        float a2[8] = {0,0,0,0,0,0,0,0};
        float a3[8] = {0,0,0,0,0,0,0,0};
        for (int base = o0; base < o1; base += 64) {
            int cnt = min(64, o1 - base);
            int idx = (base + lane < o1) ? csr[base + lane] : 0;
            if (g < 12) {
                for (int j = 0; j < cnt; j += 48) {
                    int j0 = j + g, j1 = j + 12 + g, j2 = j + 24 + g, j3 = j + 36 + g;
                    int s0 = __shfl(idx, j0 & 63);
                    int s1 = __shfl(idx, j1 & 63);
                    int s2 = __shfl(idx, j2 & 63);
                    int s3 = __shfl(idx, j3 & 63);
                    uint4 w0 = rows[(size_t)s0 * 5 + t];
                    uint4 w1 = rows[(size_t)s1 * 5 + t];
                    uint4 w2 = rows[(size_t)s2 * 5 + t];
                    uint4 w3 = rows[(size_t)s3 * 5 + t];
                    if (j0 < cnt) accum8(a0, w0);
                    if (j1 < cnt) accum8(a1, w1);
                    if (j2 < cnt) accum8(a2, w2);
                    if (j3 < cnt) accum8(a3, w3);
                }
            }
        }
        if (g < 12) {
            #pragma unroll
            for (int k = 0; k < 8; ++k) a0[k] += a1[k] + a2[k] + a3[k];
            float* p = &part[local][g][t * 8];
            ((float4*)p)[0] = make_float4(a0[0], a0[1], a0[2], a0[3]);
            ((float4*)p)[1] = make_float4(a0[4], a0[5], a0[6], a0[7]);
        }
    }
    __syncthreads();
    if (node < n && lane < D_H) {
        float inv = 1.0f / fmaxf((float)deg, 1.0f);
        float agg = 0.0f;
        #pragma unroll
        for (int gg = 0; gg < 12; ++gg) agg += part[local][gg][lane];
        size_t p = (size_t)node * D_H + lane;
        hbuf[p] = fmaxf(agg * inv + hbuf[p], 0.0f);
    }
}

// ---------------- pre2: h2 = bf16(h@W2l^T) compact; hr = h@W2r^T + b2 --------
// Same wave-slice + LDS-staging structure; hr written as FULL 40-float rows
// (cols 24..39 zeroed) so the in-place update stays fully coalesced.
__global__ void pre2(float* __restrict__ hbuf, const float* __restrict__ W2l,
                     const float* __restrict__ W2r, const float* __restrict__ b2,
                     u32* __restrict__ h2, int n) {
    __shared__ u32   h2s[64][13];   // 12 used + pad
    __shared__ float hrs[64][41];   // 40 used + pad
    int tx = threadIdx.x;
    int w  = tx >> 6;
    int l  = tx & 63;
    int node = blockIdx.x * 64 + l;
    float4 hv[10];
    if (node < n) {
        const float4* hp = (const float4*)(hbuf + (size_t)node * D_H);
        #pragma unroll
        for (int k = 0; k < 10; ++k) hv[k] = hp[k];
    } else {
        #pragma unroll
        for (int k = 0; k < 10; ++k) hv[k] = make_float4(0.f, 0.f, 0.f, 0.f);
    }
    if (w == 3) {
        #pragma unroll
        for (int c = D_OUT; c < D_H; ++c) hrs[l][c] = 0.0f;
    }
    int obase = w * 6;
    #pragma unroll
    for (int j = 0; j < 6; j += 2) {
        int o = obase + j;
        float al0 = dot10((const float4*)(W2l + o * D_H), hv);
        float al1 = dot10((const float4*)(W2l + (o + 1) * D_H), hv);
        float ar0 = dot10((const float4*)(W2r + o * D_H), hv);
        float ar1 = dot10((const float4*)(W2r + (o + 1) * D_H), hv);
        h2s[l][o >> 1] = (u32)f32_to_bf16_rne(al0) | ((u32)f32_to_bf16_rne(al1) << 16);
        hrs[l][o]     = ar0 + b2[o];
        hrs[l][o + 1] = ar1 + b2[o + 1];
    }
    __syncthreads();
    int nodes = min(64, n - blockIdx.x * 64);
    u32*   h2b = h2 + (size_t)blockIdx.x * 64 * 12;
    float* hrb = hbuf + (size_t)blockIdx.x * 64 * 40;
    for (int i = tx; i < nodes * 12; i += 256) {
        int nn = i / 12, c = i - nn * 12;
        h2b[i] = h2s[nn][c];
    }
    for (int i = tx; i < nodes * 40; i += 256) {
        int nn = i / 40, c = i - nn * 40;
        hrb[i] = hrs[nn][c];
    }
}

// ---------------- Layer 2: out = log_softmax(mean_gather(h2) + hr) -----------
__global__ void gather_node2(const u32* __restrict__ h2p,
                             const int* __restrict__ off,
                             const int* __restrict__ csr,
                             const float* __restrict__ hbuf,  // hr rows (stride 40)
                             float* __restrict__ out, int n) {
    __shared__ __align__(16) float part[4][21][D_OUT];
    __shared__ float os[4][D_OUT];
    int local = threadIdx.x >> 6;
    int lane  = threadIdx.x & 63;
    int node  = blockIdx.x * 4 + local;
    int g = lane / 3;
    int t = lane - g * 3;
    int deg = 0;
    const uint4* rows = (const uint4*)h2p;   // 3 uint4 per row
    if (node < n) {
        int o0 = off[node], o1 = off[node + 1];
        deg = o1 - o0;
        float a0[8] = {0,0,0,0,0,0,0,0};
        float a1[8] = {0,0,0,0,0,0,0,0};
        for (int base = o0; base < o1; base += 64) {
            int cnt = min(64, o1 - base);
            int idx = (base + lane < o1) ? csr[base + lane] : 0;
            if (g < 21) {
                for (int j = 0; j < cnt; j += 42) {
                    int j0 = j + g, j1 = j + 21 + g;
                    int s0 = __shfl(idx, j0 & 63);
                    int s1 = __shfl(idx, j1 & 63);
                    uint4 w0 = rows[(size_t)s0 * 3 + t];
                    uint4 w1 = rows[(size_t)s1 * 3 + t];
                    if (j0 < cnt) accum8(a0, w0);
                    if (j1 < cnt) accum8(a1, w1);
                }
            }
        }
        if (g < 21) {
            #pragma unroll
            for (int k = 0; k < 8; ++k) a0[k] += a1[k];
            float* p = &part[local][g][t * 8];
            ((float4*)p)[0] = make_float4(a0[0], a0[1], a0[2], a0[3]);
            ((float4*)p)[1] = make_float4(a0[4], a0[5], a0[6], a0[7]);
        }
    }
    __syncthreads();
    if (node < n && lane < D_OUT) {
        float inv = 1.0f / fmaxf((float)deg, 1.0f);
        float agg = 0.0f;
        #pragma unroll
        for (int gg = 0; gg < 21; ++gg) agg += part[local][gg][lane];
        os[local][lane] = agg * inv + hbuf[(size_t)node * D_H + lane];
    }
    __syncthreads();
    if (node < n && lane < D_OUT) {
        float m = -INFINITY;
        #pragma unroll
        for (int k = 0; k < D_OUT; ++k) m = fmaxf(m, os[local][k]);
        float se = 0.0f;
        #pragma unroll
        for (int k = 0; k < D_OUT; ++k) se += expf(os[local][k] - m);
        out[(size_t)node * D_OUT + lane] = os[local][lane] - m - logf(se);
    }
}

extern "C" void kernel_launch(void* const* d_in, const int* in_sizes, int n_in,
                              void* d_out, int out_size, void* d_ws, size_t ws_size,
                              hipStream_t stream) {
    const float* x   = (const float*)d_in[0];
    const int*   ei  = (const int*)d_in[1];
    const float* W1l = (const float*)d_in[2];
    const float* b1  = (const float*)d_in[3];
    const float* W1r = (const float*)d_in[4];
    const float* W2l = (const float*)d_in[5];
    const float* b2  = (const float*)d_in[6];
    const float* W2r = (const float*)d_in[7];
    float* out = (float*)d_out;

    const int n = in_sizes[0] / D_IN;      // 100000
    const int E = in_sizes[1] / 2;         // 3200000
    const int* src = ei;
    const int* dst = ei + E;

    const int B   = (n + S_NODES - 1) >> S_BITS;   // 391 buckets
    const int NB1 = (E + CH - 1) / CH;             // 391 edge blocks

    // Workspace (~38 MB):
    //  region0: n*40 f32 = 16 MB — bucketed (E u32) then xr/h/hr (buf0)
    //  xl : n*40 bf16 = 8 MB — xl then h2 (compact n*24 bf16)
    //  off: (n+1) i32 ; G: NB1*B i32 ; bktTotal/bktStart ; csr: E i32
    char* ws = (char*)d_ws;
    float* buf0     = (float*)ws;
    u32*   bucketed = (u32*)ws;      ws += (size_t)n * D_H * 4;
    u16*   xl       = (u16*)ws;
    u16*   h2       = (u16*)ws;      ws += (size_t)n * D_H * 2;
    int*   off      = (int*)ws;      ws += (((size_t)(n + 1) * 4 + 15) & ~15ull);
    int*   G        = (int*)ws;      ws += (((size_t)NB1 * B * 4 + 15) & ~15ull);
    int*   bktTotal = (int*)ws;      ws += (((size_t)B * 4 + 15) & ~15ull);
    int*   bktStart = (int*)ws;      ws += (((size_t)(B + 1) * 4 + 15) & ~15ull);
    int*   csr      = (int*)ws;

    passA<<<NB1, 256, 0, stream>>>(dst, G, E, B);
    colscan<<<B, 64, 0, stream>>>(G, bktTotal, NB1, B);
    bucketscan<<<1, 64, 0, stream>>>(bktTotal, bktStart, off, B, E, n);
    passB<<<NB1, 256, 0, stream>>>(src, dst, G, bktStart, bucketed, E, B);
    bucket_csr<<<B, 256, 0, stream>>>(bucketed, bktStart, off, csr, n);

    const int nb64 = (n + 63) / 64;
    pre1<<<nb64, 256, 0, stream>>>(x, W1l, W1r, b1, (u32*)xl, buf0, n);
    gather_node1<<<(n + 3) / 4, 256, 0, stream>>>((const u32*)xl, off, csr, buf0, n);
    pre2<<<nb64, 256, 0, stream>>>(buf0, W2l, W2r, b2, (u32*)h2, n);
    gather_node2<<<(n + 3) / 4, 256, 0, stream>>>((const u32*)h2, off, csr, buf0, out, n);
}

// Round 11
// 401.169 us; speedup vs baseline: 1.3051x; 1.3051x over previous
//
#include <hip/hip_runtime.h>
#include <math.h>

#define D_IN 64
#define D_H 40
#define D_OUT 24
#define S_BITS 8
#define S_NODES 256      // nodes per bucket
#define CH 8192          // edges per passA/passB block
#define BMAX 512         // max buckets (n <= 131072)

typedef unsigned int u32;
typedef unsigned short u16;

// ---------------- CSR build: atomic-free LDS multisplit ----------------
__global__ void passA(const int* __restrict__ dst, int* __restrict__ G,
                      int E, int B) {
    __shared__ int hist[BMAX];
    int tx = threadIdx.x;
    for (int i = tx; i < B; i += 256) hist[i] = 0;
    __syncthreads();
    int e0 = blockIdx.x * CH;
    int e1 = min(e0 + CH, E);
    for (int e = e0 + tx; e < e1; e += 256)
        atomicAdd(&hist[dst[e] >> S_BITS], 1);      // LDS atomic
    __syncthreads();
    for (int i = tx; i < B; i += 256) G[(size_t)blockIdx.x * B + i] = hist[i];
}

__global__ void colscan(int* __restrict__ G, int* __restrict__ bktTotal,
                        int NB1, int B) {
    int b = blockIdx.x;
    int lane = threadIdx.x;      // 64 threads
    int carry = 0;
    for (int base = 0; base < NB1; base += 64) {
        int i = base + lane;
        int orig = (i < NB1) ? G[(size_t)i * B + b] : 0;
        int v = orig;
        #pragma unroll
        for (int d = 1; d < 64; d <<= 1) {
            int t = __shfl_up(v, d);
            if (lane >= d) v += t;
        }
        if (i < NB1) G[(size_t)i * B + b] = carry + v - orig;   // exclusive
        carry += __shfl(v, 63);
    }
    if (lane == 0) bktTotal[b] = carry;
}

__global__ void bucketscan(const int* __restrict__ bktTotal,
                           int* __restrict__ bktStart, int* __restrict__ off,
                           int B, int E, int n) {
    int lane = threadIdx.x;
    int carry = 0;
    for (int base = 0; base < B; base += 64) {
        int i = base + lane;
        int orig = (i < B) ? bktTotal[i] : 0;
        int v = orig;
        #pragma unroll
        for (int d = 1; d < 64; d <<= 1) {
            int t = __shfl_up(v, d);
            if (lane >= d) v += t;
        }
        if (i < B) bktStart[i] = carry + v - orig;
        carry += __shfl(v, 63);
    }
    if (lane == 0) { bktStart[B] = carry; off[n] = E; }
}

__global__ void passB(const int* __restrict__ src, const int* __restrict__ dst,
                      const int* __restrict__ G, const int* __restrict__ bktStart,
                      u32* __restrict__ bucketed, int E, int B) {
    __shared__ int baseS[BMAX];
    __shared__ int cnt[BMAX];
    int tx = threadIdx.x;
    for (int i = tx; i < B; i += 256) {
        baseS[i] = bktStart[i] + G[(size_t)blockIdx.x * B + i];
        cnt[i] = 0;
    }
    __syncthreads();
    int e0 = blockIdx.x * CH;
    int e1 = min(e0 + CH, E);
    for (int e = e0 + tx; e < e1; e += 256) {
        int d = dst[e];
        int b = d >> S_BITS;
        int r = atomicAdd(&cnt[b], 1);               // LDS atomic
        bucketed[baseS[b] + r] = ((u32)(d & (S_NODES - 1)) << 24) | (u32)src[e];
    }
}

__global__ void bucket_csr(const u32* __restrict__ bucketed,
                           const int* __restrict__ bktStart,
                           int* __restrict__ off, int* __restrict__ csr,
                           int n) {
    __shared__ int degl[S_NODES];
    __shared__ int offl[S_NODES + 1];
    __shared__ int cntl[S_NODES];
    int b  = blockIdx.x;
    int tx = threadIdx.x;        // 256
    int bs = bktStart[b], be = bktStart[b + 1];
    degl[tx] = 0;
    cntl[tx] = 0;
    __syncthreads();
    for (int e = bs + tx; e < be; e += 256)
        atomicAdd(&degl[bucketed[e] >> 24], 1);      // LDS atomic
    __syncthreads();
    int v = degl[tx];
    offl[tx] = v;
    __syncthreads();
    for (int d = 1; d < 256; d <<= 1) {
        int t = (tx >= d) ? offl[tx - d] : 0;
        __syncthreads();
        offl[tx] += t;
        __syncthreads();
    }
    int excl = offl[tx] - v;
    __syncthreads();
    offl[tx] = excl;
    if (tx == 255) offl[256] = excl + v;
    __syncthreads();
    int node = b * S_NODES + tx;
    if (node <= n) off[node] = bs + offl[tx];
    for (int e = bs + tx; e < be; e += 256) {
        u32 w = bucketed[e];
        int dl = w >> 24;
        int r = atomicAdd(&cntl[dl], 1);             // LDS atomic
        csr[bs + offl[dl] + r] = (int)(w & 0xFFFFFFu);
    }
}

// ---------------- bf16 helpers ----------------
__device__ inline u16 f32_to_bf16_rne(float f) {
    u32 u = __float_as_uint(f);
    u += 0x7fffu + ((u >> 16) & 1u);
    return (u16)(u >> 16);
}

__device__ inline void accum8(float* a, uint4 w) {
    a[0] += __uint_as_float(w.x << 16);
    a[1] += __uint_as_float(w.x & 0xffff0000u);
    a[2] += __uint_as_float(w.y << 16);
    a[3] += __uint_as_float(w.y & 0xffff0000u);
    a[4] += __uint_as_float(w.z << 16);
    a[5] += __uint_as_float(w.z & 0xffff0000u);
    a[6] += __uint_as_float(w.w << 16);
    a[7] += __uint_as_float(w.w & 0xffff0000u);
}

// fma float4 into scalar acc
__device__ inline void fma4(float& acc, float4 w, float4 v) {
    acc = fmaf(w.x, v.x, acc);
    acc = fmaf(w.y, v.y, acc);
    acc = fmaf(w.z, v.z, acc);
    acc = fmaf(w.w, v.w, acc);
}

// ---------------- pre1: xl = bf16(x@W1l^T), xr = x@W1r^T + b1 ----------------
// Block = 64 nodes x 4 waves. x tile staged chunk-major in LDS (compute reads
// lane-contiguous, conflict-free). Wave w computes outputs [w*10,w*10+10) for
// all 64 nodes with 4 accumulators per o-pair (no big register arrays -> no
// spill). Outputs staged in LDS, written lane-linear (clean WRITE_SIZE).
__global__ void pre1(const float* __restrict__ x, const float* __restrict__ W1l,
                     const float* __restrict__ W1r, const float* __restrict__ b1,
                     u32* __restrict__ xl, float* __restrict__ xr, int n) {
    __shared__ float4 xsT[16][64];   // chunk-major x tile
    __shared__ u32    xls[64][21];   // 20 used + pad
    __shared__ float  xrs[64][41];   // 40 used + pad
    int tx = threadIdx.x;
    int w  = tx >> 6;
    int l  = tx & 63;
    int base = blockIdx.x * 64;
    int nodes = min(64, n - base);
    // Phase 1: coalesced tile load (linear global float4s -> transposed LDS)
    const float4* xg = (const float4*)(x + (size_t)base * D_IN);
    for (int i = tx; i < nodes * 16; i += 256) {
        int nn = i >> 4, c = i & 15;
        xsT[c][nn] = xg[i];
    }
    __syncthreads();
    // Phase 2: wave w -> outputs [w*10, w*10+10)
    int obase = w * 10;
    #pragma unroll
    for (int j = 0; j < 10; j += 2) {
        int o = obase + j;
        float al0 = 0.f, al1 = 0.f, ar0 = 0.f, ar1 = 0.f;
        const float4* wl0 = (const float4*)(W1l + (size_t)o * D_IN);
        const float4* wl1 = (const float4*)(W1l + (size_t)(o + 1) * D_IN);
        const float4* wr0 = (const float4*)(W1r + (size_t)o * D_IN);
        const float4* wr1 = (const float4*)(W1r + (size_t)(o + 1) * D_IN);
        #pragma unroll
        for (int k = 0; k < 16; ++k) {
            float4 v = xsT[k][l];
            fma4(al0, wl0[k], v);
            fma4(al1, wl1[k], v);
            fma4(ar0, wr0[k], v);
            fma4(ar1, wr1[k], v);
        }
        xls[l][o >> 1] = (u32)f32_to_bf16_rne(al0) | ((u32)f32_to_bf16_rne(al1) << 16);
        xrs[l][o]     = ar0 + b1[o];
        xrs[l][o + 1] = ar1 + b1[o + 1];
    }
    __syncthreads();
    // Phase 3: lane-linear coalesced writes
    u32*   xlb = xl + (size_t)base * 20;
    float* xrb = xr + (size_t)base * 40;
    for (int i = tx; i < nodes * 20; i += 256) {
        int nn = i / 20, c = i - nn * 20;
        xlb[i] = xls[nn][c];
    }
    for (int i = tx; i < nodes * 40; i += 256) {
        int nn = i / 40, c = i - nn * 40;
        xrb[i] = xrs[nn][c];
    }
}

// ---------------- Layer 1: h = relu(mean_gather(xl) + xr), in-place on xr ----
__global__ void gather_node1(const u32* __restrict__ xlp,
                             const int* __restrict__ off,
                             const int* __restrict__ csr,
                             float* __restrict__ hbuf,  // xr in, h out (n x 40)
                             int n) {
    __shared__ __align__(16) float part[4][12][D_H];
    int local = threadIdx.x >> 6;
    int lane  = threadIdx.x & 63;
    int node  = blockIdx.x * 4 + local;
    int g = lane / 5;
    int t = lane - g * 5;
    int deg = 0;
    const uint4* rows = (const uint4*)xlp;   // 5 uint4 per row
    if (node < n) {
        int o0 = off[node], o1 = off[node + 1];
        deg = o1 - o0;
        float a0[8] = {0,0,0,0,0,0,0,0};
        float a1[8] = {0,0,0,0,0,0,0,0};
        float a2[8] = {0,0,0,0,0,0,0,0};
        float a3[8] = {0,0,0,0,0,0,0,0};
        for (int base = o0; base < o1; base += 64) {
            int cnt = min(64, o1 - base);
            int idx = (base + lane < o1) ? csr[base + lane] : 0;
            if (g < 12) {
                for (int j = 0; j < cnt; j += 48) {
                    int j0 = j + g, j1 = j + 12 + g, j2 = j + 24 + g, j3 = j + 36 + g;
                    int s0 = __shfl(idx, j0 & 63);
                    int s1 = __shfl(idx, j1 & 63);
                    int s2 = __shfl(idx, j2 & 63);
                    int s3 = __shfl(idx, j3 & 63);
                    uint4 w0 = rows[(size_t)s0 * 5 + t];
                    uint4 w1 = rows[(size_t)s1 * 5 + t];
                    uint4 w2 = rows[(size_t)s2 * 5 + t];
                    uint4 w3 = rows[(size_t)s3 * 5 + t];
                    if (j0 < cnt) accum8(a0, w0);
                    if (j1 < cnt) accum8(a1, w1);
                    if (j2 < cnt) accum8(a2, w2);
                    if (j3 < cnt) accum8(a3, w3);
                }
            }
        }
        if (g < 12) {
            #pragma unroll
            for (int k = 0; k < 8; ++k) a0[k] += a1[k] + a2[k] + a3[k];
            float* p = &part[local][g][t * 8];
            ((float4*)p)[0] = make_float4(a0[0], a0[1], a0[2], a0[3]);
            ((float4*)p)[1] = make_float4(a0[4], a0[5], a0[6], a0[7]);
        }
    }
    __syncthreads();
    if (node < n && lane < D_H) {
        float inv = 1.0f / fmaxf((float)deg, 1.0f);
        float agg = 0.0f;
        #pragma unroll
        for (int gg = 0; gg < 12; ++gg) agg += part[local][gg][lane];
        size_t p = (size_t)node * D_H + lane;
        hbuf[p] = fmaxf(agg * inv + hbuf[p], 0.0f);
    }
}

// ---------------- pre2: h2 = bf16(h@W2l^T) compact; hr = h@W2r^T + b2 --------
// Same structure as pre1; hr written as FULL 40-float rows (cols 24..39 = 0)
// directly from the epilogue so the in-place update stays fully coalesced.
__global__ void pre2(float* __restrict__ hbuf, const float* __restrict__ W2l,
                     const float* __restrict__ W2r, const float* __restrict__ b2,
                     u32* __restrict__ h2, int n) {
    __shared__ float4 hsT[10][64];   // chunk-major h tile
    __shared__ u32    h2s[64][13];   // 12 used + pad
    __shared__ float  hrs[64][25];   // 24 used + pad
    int tx = threadIdx.x;
    int w  = tx >> 6;
    int l  = tx & 63;
    int base = blockIdx.x * 64;
    int nodes = min(64, n - base);
    const float4* hg = (const float4*)(hbuf + (size_t)base * D_H);
    for (int i = tx; i < nodes * 10; i += 256) {
        int nn = i / 10, c = i - nn * 10;
        hsT[c][nn] = hg[i];
    }
    __syncthreads();
    int obase = w * 6;
    #pragma unroll
    for (int j = 0; j < 6; j += 2) {
        int o = obase + j;
        float al0 = 0.f, al1 = 0.f, ar0 = 0.f, ar1 = 0.f;
        const float4* wl0 = (const float4*)(W2l + (size_t)o * D_H);
        const float4* wl1 = (const float4*)(W2l + (size_t)(o + 1) * D_H);
        const float4* wr0 = (const float4*)(W2r + (size_t)o * D_H);
        const float4* wr1 = (const float4*)(W2r + (size_t)(o + 1) * D_H);
        #pragma unroll
        for (int k = 0; k < 10; ++k) {
            float4 v = hsT[k][l];
            fma4(al0, wl0[k], v);
            fma4(al1, wl1[k], v);
            fma4(ar0, wr0[k], v);
            fma4(ar1, wr1[k], v);
        }
        h2s[l][o >> 1] = (u32)f32_to_bf16_rne(al0) | ((u32)f32_to_bf16_rne(al1) << 16);
        hrs[l][o]     = ar0 + b2[o];
        hrs[l][o + 1] = ar1 + b2[o + 1];
    }
    __syncthreads();
    u32*   h2b = h2 + (size_t)base * 12;
    float* hrb = hbuf + (size_t)base * 40;
    for (int i = tx; i < nodes * 12; i += 256) {
        int nn = i / 12, c = i - nn * 12;
        h2b[i] = h2s[nn][c];
    }
    for (int i = tx; i < nodes * 40; i += 256) {
        int nn = i / 40, c = i - nn * 40;
        hrb[i] = (c < D_OUT) ? hrs[nn][c] : 0.0f;
    }
}

// ---------------- Layer 2: out = log_softmax(mean_gather(h2) + hr) -----------
__global__ void gather_node2(const u32* __restrict__ h2p,
                             const int* __restrict__ off,
                             const int* __restrict__ csr,
                             const float* __restrict__ hbuf,  // hr rows (stride 40)
                             float* __restrict__ out, int n) {
    __shared__ __align__(16) float part[4][21][D_OUT];
    __shared__ float os[4][D_OUT];
    int local = threadIdx.x >> 6;
    int lane  = threadIdx.x & 63;
    int node  = blockIdx.x * 4 + local;
    int g = lane / 3;
    int t = lane - g * 3;
    int deg = 0;
    const uint4* rows = (const uint4*)h2p;   // 3 uint4 per row
    if (node < n) {
        int o0 = off[node], o1 = off[node + 1];
        deg = o1 - o0;
        float a0[8] = {0,0,0,0,0,0,0,0};
        float a1[8] = {0,0,0,0,0,0,0,0};
        for (int base = o0; base < o1; base += 64) {
            int cnt = min(64, o1 - base);
            int idx = (base + lane < o1) ? csr[base + lane] : 0;
            if (g < 21) {
                for (int j = 0; j < cnt; j += 42) {
                    int j0 = j + g, j1 = j + 21 + g;
                    int s0 = __shfl(idx, j0 & 63);
                    int s1 = __shfl(idx, j1 & 63);
                    uint4 w0 = rows[(size_t)s0 * 3 + t];
                    uint4 w1 = rows[(size_t)s1 * 3 + t];
                    if (j0 < cnt) accum8(a0, w0);
                    if (j1 < cnt) accum8(a1, w1);
                }
            }
        }
        if (g < 21) {
            #pragma unroll
            for (int k = 0; k < 8; ++k) a0[k] += a1[k];
            float* p = &part[local][g][t * 8];
            ((float4*)p)[0] = make_float4(a0[0], a0[1], a0[2], a0[3]);
            ((float4*)p)[1] = make_float4(a0[4], a0[5], a0[6], a0[7]);
        }
    }
    __syncthreads();
    if (node < n && lane < D_OUT) {
        float inv = 1.0f / fmaxf((float)deg, 1.0f);
        float agg = 0.0f;
        #pragma unroll
        for (int gg = 0; gg < 21; ++gg) agg += part[local][gg][lane];
        os[local][lane] = agg * inv + hbuf[(size_t)node * D_H + lane];
    }
    __syncthreads();
    if (node < n && lane < D_OUT) {
        float m = -INFINITY;
        #pragma unroll
        for (int k = 0; k < D_OUT; ++k) m = fmaxf(m, os[local][k]);
        float se = 0.0f;
        #pragma unroll
        for (int k = 0; k < D_OUT; ++k) se += expf(os[local][k] - m);
        out[(size_t)node * D_OUT + lane] = os[local][lane] - m - logf(se);
    }
}

extern "C" void kernel_launch(void* const* d_in, const int* in_sizes, int n_in,
                              void* d_out, int out_size, void* d_ws, size_t ws_size,
                              hipStream_t stream) {
    const float* x   = (const float*)d_in[0];
    const int*   ei  = (const int*)d_in[1];
    const float* W1l = (const float*)d_in[2];
    const float* b1  = (const float*)d_in[3];
    const float* W1r = (const float*)d_in[4];
    const float* W2l = (const float*)d_in[5];
    const float* b2  = (const float*)d_in[6];
    const float* W2r = (const float*)d_in[7];
    float* out = (float*)d_out;

    const int n = in_sizes[0] / D_IN;      // 100000
    const int E = in_sizes[1] / 2;         // 3200000
    const int* src = ei;
    const int* dst = ei + E;

    const int B   = (n + S_NODES - 1) >> S_BITS;   // 391 buckets
    const int NB1 = (E + CH - 1) / CH;             // 391 edge blocks

    // Workspace (~38 MB):
    //  region0: n*40 f32 = 16 MB — bucketed (E u32) then xr/h/hr (buf0)
    //  xl : n*40 bf16 = 8 MB — xl then h2 (compact n*24 bf16)
    //  off: (n+1) i32 ; G: NB1*B i32 ; bktTotal/bktStart ; csr: E i32
    char* ws = (char*)d_ws;
    float* buf0     = (float*)ws;
    u32*   bucketed = (u32*)ws;      ws += (size_t)n * D_H * 4;
    u16*   xl       = (u16*)ws;
    u16*   h2       = (u16*)ws;      ws += (size_t)n * D_H * 2;
    int*   off      = (int*)ws;      ws += (((size_t)(n + 1) * 4 + 15) & ~15ull);
    int*   G        = (int*)ws;      ws += (((size_t)NB1 * B * 4 + 15) & ~15ull);
    int*   bktTotal = (int*)ws;      ws += (((size_t)B * 4 + 15) & ~15ull);
    int*   bktStart = (int*)ws;      ws += (((size_t)(B + 1) * 4 + 15) & ~15ull);
    int*   csr      = (int*)ws;

    passA<<<NB1, 256, 0, stream>>>(dst, G, E, B);
    colscan<<<B, 64, 0, stream>>>(G, bktTotal, NB1, B);
    bucketscan<<<1, 64, 0, stream>>>(bktTotal, bktStart, off, B, E, n);
    passB<<<NB1, 256, 0, stream>>>(src, dst, G, bktStart, bucketed, E, B);
    bucket_csr<<<B, 256, 0, stream>>>(bucketed, bktStart, off, csr, n);

    const int nb64 = (n + 63) / 64;
    pre1<<<nb64, 256, 0, stream>>>(x, W1l, W1r, b1, (u32*)xl, buf0, n);
    gather_node1<<<(n + 3) / 4, 256, 0, stream>>>((const u32*)xl, off, csr, buf0, n);
    pre2<<<nb64, 256, 0, stream>>>(buf0, W2l, W2r, b2, (u32*)h2, n);
    gather_node2<<<(n + 3) / 4, 256, 0, stream>>>((const u32*)h2, off, csr, buf0, out, n);
}